// Round 8
// baseline (142.550 us; speedup 1.0000x reference)
//
#include <hip/hip_runtime.h>
#include <hip/hip_bf16.h>

#define SL     32768
#define EPS_LN 1e-5f

typedef unsigned short u16;
typedef __attribute__((ext_vector_type(8))) short bf16x8;
typedef __attribute__((ext_vector_type(4))) float f32x4;

#define MFMA16(a, b, c) __builtin_amdgcn_mfma_f32_16x16x32_bf16((a), (b), (c), 0, 0, 0)

__device__ inline u16 f2bf(float f) {
    __hip_bfloat16 h = __float2bfloat16(f);
    return *reinterpret_cast<u16*>(&h);
}
__device__ inline float bf2f(u16 u) {
    unsigned v = ((unsigned)u) << 16;
    float f;
    __builtin_memcpy(&f, &v, 4);
    return f;
}
__device__ inline uint4 pack8(float4 a, float4 b) {
    union { uint4 v; u16 u[8]; } U;
    U.u[0] = f2bf(a.x); U.u[1] = f2bf(a.y); U.u[2] = f2bf(a.z); U.u[3] = f2bf(a.w);
    U.u[4] = f2bf(b.x); U.u[5] = f2bf(b.y); U.u[6] = f2bf(b.z); U.u[7] = f2bf(b.w);
    return U.v;
}

// ---------------------------------------------------------------------------
// QKV via MFMA. grid 1536 = 3 o-tiles(128) x 512 n-tiles(64). Block stages
// x-tile (converted to bf16) + w o-tile (fp32->bf16), 32 MFMA/wave, writes.
// T = float (pass 1) or u16 (pass 2) input.
// ---------------------------------------------------------------------------
template<typename T>
__global__ __launch_bounds__(256) void qkv_mfma(const T* __restrict__ in,
                                                const float* __restrict__ wq,
                                                const float* __restrict__ bq,
                                                u16* __restrict__ qkv) {
    __shared__ u16 wT[128][136];
    __shared__ u16 xT[64][136];
    __shared__ float bs[128];
    __shared__ u16 outT[128][72];
    const int bid = blockIdx.x;
    const int o0 = (bid % 3) * 128;
    const int n0 = (bid / 3) * 64;
    const int t = threadIdx.x;

    // stage x transposed [n][d]; contiguous-segment mapping (8 lanes/row)
    #pragma unroll
    for (int itr = 0; itr < 4; ++itr) {
        const int u = t + itr * 256;
        const int d = u >> 3, noct = u & 7;
        if constexpr (sizeof(T) == 4) {
            const float* src = (const float*)in + (size_t)d * SL + n0 + noct * 8;
            float4 f0 = *(const float4*)src;
            float4 f1 = *(const float4*)(src + 4);
            xT[noct * 8 + 0][d] = f2bf(f0.x);
            xT[noct * 8 + 1][d] = f2bf(f0.y);
            xT[noct * 8 + 2][d] = f2bf(f0.z);
            xT[noct * 8 + 3][d] = f2bf(f0.w);
            xT[noct * 8 + 4][d] = f2bf(f1.x);
            xT[noct * 8 + 5][d] = f2bf(f1.y);
            xT[noct * 8 + 6][d] = f2bf(f1.z);
            xT[noct * 8 + 7][d] = f2bf(f1.w);
        } else {
            union { uint4 v; u16 s[8]; } U;
            U.v = *(const uint4*)((const u16*)in + (size_t)d * SL + n0 + noct * 8);
            #pragma unroll
            for (int j = 0; j < 8; ++j) xT[noct * 8 + j][d] = U.s[j];
        }
    }
    // stage w [o][k] fp32 -> bf16, coalesced (8 lanes x 16 elems per row)
    #pragma unroll
    for (int itr = 0; itr < 4; ++itr) {
        const int o = itr * 32 + (t >> 3);
        const int f = (t & 7) * 16;
        const float* src = wq + (size_t)(o0 + o) * 128 + f;
        float4 a = *(const float4*)src;
        float4 b = *(const float4*)(src + 4);
        float4 c = *(const float4*)(src + 8);
        float4 d2 = *(const float4*)(src + 12);
        *(uint4*)&wT[o][f] = pack8(a, b);
        *(uint4*)&wT[o][f + 8] = pack8(c, d2);
    }
    if (t < 128) bs[t] = bq[o0 + t];
    __syncthreads();

    const int lane = t & 63, wv = t >> 6, lo = lane & 15, hi = lane >> 4;

    bf16x8 af[2][4];
    #pragma unroll
    for (int om = 0; om < 2; ++om)
        #pragma unroll
        for (int ks = 0; ks < 4; ++ks)
            af[om][ks] = *(const bf16x8*)&wT[wv * 32 + om * 16 + lo][hi * 8 + ks * 32];

    #pragma unroll
    for (int nt = 0; nt < 4; ++nt) {
        bf16x8 bfr[4];
        #pragma unroll
        for (int ks = 0; ks < 4; ++ks)
            bfr[ks] = *(const bf16x8*)&xT[nt * 16 + lo][hi * 8 + ks * 32];
        #pragma unroll
        for (int om = 0; om < 2; ++om) {
            f32x4 acc = {0.f, 0.f, 0.f, 0.f};
            #pragma unroll
            for (int ks = 0; ks < 4; ++ks)
                acc = MFMA16(af[om][ks], bfr[ks], acc);
            #pragma unroll
            for (int r = 0; r < 4; ++r) {
                const int orow = wv * 32 + om * 16 + hi * 4 + r;
                outT[orow][nt * 16 + lo] = f2bf(acc[r] + bs[orow]);
            }
        }
    }
    __syncthreads();
    {   // coalesced store: 64 B per thread
        const int o = t >> 1, nh = (t & 1) * 32;
        u16* dst = qkv + (size_t)(o0 + o) * SL + n0 + nh;
        const uint4* s4 = (const uint4*)&outT[o][nh];
        #pragma unroll
        for (int k = 0; k < 4; ++k) ((uint4*)dst)[k] = s4[k];
    }
}

// ---------------------------------------------------------------------------
// Fused attention via MFMA. Per-i-tile blocks (max parallelism), coalesced
// staging. grid = H * NOUT * IT = 2048 for both KLENs.
// ---------------------------------------------------------------------------
template<int KLEN>
__global__ __launch_bounds__(256) void attn_kernel(const u16* __restrict__ qkv,
                                                   u16* __restrict__ ao) {
    constexpr int NJT = KLEN / 16;
    constexpr int JS = KLEN / 8;    // 16B segments per row
    constexpr int IT = (KLEN == 256) ? 4 : 2;
    constexpr int NOUT = SL / KLEN;
    __shared__ u16 QT[64][40];
    __shared__ u16 KT[KLEN][40];
    __shared__ u16 VT[32][KLEN + 8];
    __shared__ u16 PT[64][40];

    const int bid = blockIdx.x;
    const int it = bid & (IT - 1);
    const int outer = (bid / IT) % NOUT;
    const int h = bid / (IT * NOUT);
    const int base = outer * KLEN;
    const int i0 = it * 64;
    const int t = threadIdx.x;

    {   // stage Q transposed [i][c]: 32 c x 8 segs, lanes walk i
        const int c = t >> 3, iseg = t & 7;
        union { uint4 v; u16 s[8]; } u;
        u.v = *(const uint4*)(qkv + (size_t)(h * 32 + c) * SL + base + i0 + iseg * 8);
        #pragma unroll
        for (int j = 0; j < 8; ++j) QT[iseg * 8 + j][c] = u.s[j];
    }
    #pragma unroll
    for (int itr = 0; itr < KLEN / 64; ++itr) {   // K transposed [j][c]
        const int u0 = t + itr * 256;
        const int c = u0 / JS, jseg = u0 % JS;
        union { uint4 v; u16 s[8]; } u;
        u.v = *(const uint4*)(qkv + (size_t)(128 + h * 32 + c) * SL + base + jseg * 8);
        #pragma unroll
        for (int j = 0; j < 8; ++j) KT[jseg * 8 + j][c] = u.s[j];
    }
    #pragma unroll
    for (int itr = 0; itr < KLEN / 64; ++itr) {   // V native [c][j]
        const int u0 = t + itr * 256;
        const int c = u0 / JS, jseg = u0 % JS;
        *(uint4*)&VT[c][jseg * 8] =
            *(const uint4*)(qkv + (size_t)(256 + h * 32 + c) * SL + base + jseg * 8);
    }
    __syncthreads();

    const int lane = t & 63, wv = t >> 6, lo = lane & 15, hi = lane >> 4;

    bf16x8 qfrag = *(const bf16x8*)&QT[wv * 16 + lo][hi * 8];
    f32x4 oacc0 = {0.f, 0.f, 0.f, 0.f}, oacc1 = {0.f, 0.f, 0.f, 0.f};
    float lsum[4] = {0.f, 0.f, 0.f, 0.f};

    #pragma unroll
    for (int jt = 0; jt < NJT; ++jt) {
        bf16x8 kfrag = *(const bf16x8*)&KT[jt * 16 + lo][hi * 8];
        f32x4 z = {0.f, 0.f, 0.f, 0.f};
        f32x4 s = MFMA16(qfrag, kfrag, z);
        #pragma unroll
        for (int r = 0; r < 4; ++r) {
            float p = __expf(s[r]);
            lsum[r] += p;
            PT[wv * 16 + hi * 4 + r][(jt & 1) * 16 + lo] = f2bf(p);
        }
        if (jt & 1) {
            bf16x8 pfrag = *(const bf16x8*)&PT[wv * 16 + lo][hi * 8];
            const int jb = (jt - 1) * 16;
            bf16x8 v0 = *(const bf16x8*)&VT[lo][jb + hi * 8];
            bf16x8 v1 = *(const bf16x8*)&VT[16 + lo][jb + hi * 8];
            oacc0 = MFMA16(pfrag, v0, oacc0);
            oacc1 = MFMA16(pfrag, v1, oacc1);
        }
    }
    #pragma unroll
    for (int r = 0; r < 4; ++r) {
        float v = lsum[r];
        v += __shfl_xor(v, 1);
        v += __shfl_xor(v, 2);
        v += __shfl_xor(v, 4);
        v += __shfl_xor(v, 8);
        lsum[r] = 1.f / v;
    }
    __syncthreads();   // all waves done with KT -> overlay output
    u16 (*OTu)[72] = (u16 (*)[72])&KT[0][0];   // [32 d][64 i] bf16
    #pragma unroll
    for (int r = 0; r < 4; ++r) {
        OTu[lo][wv * 16 + hi * 4 + r]      = f2bf(oacc0[r] * lsum[r]);
        OTu[16 + lo][wv * 16 + hi * 4 + r] = f2bf(oacc1[r] * lsum[r]);
    }
    __syncthreads();
    {   // coalesced store
        const int d = t >> 3, seg = t & 7;
        u16* dst = ao + (size_t)(h * 32 + d) * SL + base + i0 + seg * 8;
        *(uint4*)dst = *(uint4*)&OTu[d][seg * 8];
    }
}

// ---------------------------------------------------------------------------
// Fused LN: stats + normalize + transpose in one kernel.
// grid 512, block 256. Tile = 4 rows x 16 cols (NIN layout) x all 128 d.
// Phase A: stage val=(in0+in1) to LDS [128][69] while 4 thr/pos accumulate
// sum/sumsq. Merge -> per-pos mean/rstd. Phase B: normalize from LDS, write
// transposed: out[d][c*NOUT + r].
// ---------------------------------------------------------------------------
template<int NIN, typename T0, typename TO>
__global__ __launch_bounds__(256) void ln_fused(const T0* __restrict__ in0,
                                                const u16* __restrict__ in1,
                                                const float* __restrict__ g,
                                                const float* __restrict__ be,
                                                TO* __restrict__ outp) {
    constexpr int NOUT = SL / NIN;
    constexpr int CT = NIN / 16;
    __shared__ float val[128][69];
    __shared__ float redS[4][72];
    __shared__ float redQ[4][72];
    __shared__ float stat[64][2];
    const int bid = blockIdx.x;
    const int r0 = (bid / CT) * 4;
    const int c0 = (bid % CT) * 16;
    const int t = threadIdx.x;
    const int pos = t & 63, q = t >> 6;
    const size_t gp = (size_t)(r0 + (pos >> 4)) * NIN + c0 + (pos & 15);

    float s = 0.f, ss = 0.f;
    #pragma unroll 4
    for (int dd = 0; dd < 32; ++dd) {
        const int d = q * 32 + dd;
        float v;
        if constexpr (sizeof(T0) == 4) v = ((const float*)in0)[(size_t)d * SL + gp];
        else                           v = bf2f(((const u16*)in0)[(size_t)d * SL + gp]);
        v += bf2f(in1[(size_t)d * SL + gp]);
        val[d][pos] = v;
        s += v; ss += v * v;
    }
    redS[q][pos] = s;
    redQ[q][pos] = ss;
    __syncthreads();
    if (t < 64) {
        const float S  = redS[0][t] + redS[1][t] + redS[2][t] + redS[3][t];
        const float SS = redQ[0][t] + redQ[1][t] + redQ[2][t] + redQ[3][t];
        const float mean = S * (1.f / 128.f);
        const float var  = SS * (1.f / 128.f) - mean * mean;
        stat[t][0] = mean;
        stat[t][1] = rsqrtf(var + EPS_LN);
    }
    __syncthreads();

    {   // write phase: thread = (d = t>>1, 8 c's)
        const int d = t >> 1;
        const int ch = (t & 1) * 8;
        const float gd = g[d], bd = be[d];
        #pragma unroll
        for (int cc = 0; cc < 8; ++cc) {
            const int c = ch + cc;
            float ov[4];
            #pragma unroll
            for (int r = 0; r < 4; ++r) {
                const int p = r * 16 + c;
                ov[r] = (val[d][p] - stat[p][0]) * stat[p][1] * gd + bd;
            }
            if constexpr (sizeof(TO) == 4) {
                float* dst = (float*)outp + (size_t)d * SL + (c0 + c) * NOUT + r0;
                *(float4*)dst = make_float4(ov[0], ov[1], ov[2], ov[3]);
            } else {
                u16* dst = (u16*)outp + (size_t)d * SL + (c0 + c) * NOUT + r0;
                ushort4 o4;
                o4.x = f2bf(ov[0]); o4.y = f2bf(ov[1]);
                o4.z = f2bf(ov[2]); o4.w = f2bf(ov[3]);
                *(ushort4*)dst = o4;
            }
        }
    }
}

// ---------------------------------------------------------------------------
extern "C" void kernel_launch(void* const* d_in, const int* in_sizes, int n_in,
                              void* d_out, int out_size, void* d_ws, size_t ws_size,
                              hipStream_t stream) {
    const float* x     = (const float*)d_in[0];
    const float* w_row = (const float*)d_in[1];
    const float* b_row = (const float*)d_in[2];
    const float* w_col = (const float*)d_in[3];
    const float* b_col = (const float*)d_in[4];
    const float* g1    = (const float*)d_in[5];
    const float* be1   = (const float*)d_in[6];
    const float* g2    = (const float*)d_in[7];
    const float* be2   = (const float*)d_in[8];
    float* out = (float*)d_out;

    // ws: qkv 24MB | ao 8MB | o1b 8MB
    char* base = (char*)d_ws;
    u16* qkvb = (u16*)base;                       base += (size_t)384 * SL * 2;
    u16* ao16 = (u16*)base;                       base += (size_t)128 * SL * 2;
    u16* o1b  = (u16*)base;

    qkv_mfma<float><<<1536, 256, 0, stream>>>(x, w_row, b_row, qkvb);
    attn_kernel<256><<<2048, 256, 0, stream>>>(qkvb, ao16);
    ln_fused<256, float, u16><<<512, 256, 0, stream>>>(x, ao16, g1, be1, o1b);
    qkv_mfma<u16><<<1536, 256, 0, stream>>>(o1b, w_col, b_col, qkvb);
    attn_kernel<128><<<2048, 256, 0, stream>>>(qkvb, ao16);
    ln_fused<128, u16, float><<<512, 256, 0, stream>>>(o1b, ao16, g2, be2, out);
}

// Round 9
// 119.702 us; speedup vs baseline: 1.1909x; 1.1909x over previous
//
#include <hip/hip_runtime.h>
#include <hip/hip_bf16.h>

#define SL     32768
#define EPS_LN 1e-5f

typedef unsigned short u16;
typedef __attribute__((ext_vector_type(8))) short bf16x8;
typedef __attribute__((ext_vector_type(4))) float f32x4;

#define MFMA16(a, b, c) __builtin_amdgcn_mfma_f32_16x16x32_bf16((a), (b), (c), 0, 0, 0)

__device__ inline u16 f2bf(float f) {
    __hip_bfloat16 h = __float2bfloat16(f);
    return *reinterpret_cast<u16*>(&h);
}
__device__ inline float bf2f(u16 u) {
    unsigned v = ((unsigned)u) << 16;
    float f;
    __builtin_memcpy(&f, &v, 4);
    return f;
}
__device__ inline uint4 pack8(float4 a, float4 b) {
    union { uint4 v; u16 u[8]; } U;
    U.u[0] = f2bf(a.x); U.u[1] = f2bf(a.y); U.u[2] = f2bf(a.z); U.u[3] = f2bf(a.w);
    U.u[4] = f2bf(b.x); U.u[5] = f2bf(b.y); U.u[6] = f2bf(b.z); U.u[7] = f2bf(b.w);
    return U.v;
}

// ---------------------------------------------------------------------------
// QKV via MFMA. grid 1536 = 3 o-tiles(128) x 512 n-tiles(64).
// o-tile 0 -> Q stored TRANSPOSED qT[h][n][32] (direct from acc, ushort4)
// o-tile 1 -> K stored TRANSPOSED kT[h][n][32]
// o-tile 2 -> V stored native   vb[c128][n]   (scalar u16 stores)
// Wave w covers o rows w*32..+31 => head h == w for Q/K tiles.
// ---------------------------------------------------------------------------
template<typename T>
__global__ __launch_bounds__(256) void qkv_mfma(const T* __restrict__ in,
                                                const float* __restrict__ wq,
                                                const float* __restrict__ bq,
                                                u16* __restrict__ qT,
                                                u16* __restrict__ kT,
                                                u16* __restrict__ vb) {
    __shared__ u16 wT[128][136];
    __shared__ u16 xT[64][136];
    __shared__ float bs[128];
    const int bid = blockIdx.x;
    const int ot = bid % 3;
    const int o0 = ot * 128;
    const int n0 = (bid / 3) * 64;
    const int t = threadIdx.x;

    // stage x transposed [n][d]; conflict-free map (64 d-lanes per wave)
    #pragma unroll
    for (int itr = 0; itr < 4; ++itr) {
        const int u = t + itr * 256;
        const int d = u & 127, noct = u >> 7;   // noct 0..7
        if constexpr (sizeof(T) == 4) {
            const float* src = (const float*)in + (size_t)d * SL + n0 + noct * 8;
            float4 f0 = *(const float4*)src;
            float4 f1 = *(const float4*)(src + 4);
            xT[noct * 8 + 0][d] = f2bf(f0.x);
            xT[noct * 8 + 1][d] = f2bf(f0.y);
            xT[noct * 8 + 2][d] = f2bf(f0.z);
            xT[noct * 8 + 3][d] = f2bf(f0.w);
            xT[noct * 8 + 4][d] = f2bf(f1.x);
            xT[noct * 8 + 5][d] = f2bf(f1.y);
            xT[noct * 8 + 6][d] = f2bf(f1.z);
            xT[noct * 8 + 7][d] = f2bf(f1.w);
        } else {
            union { uint4 v; u16 s[8]; } U;
            U.v = *(const uint4*)((const u16*)in + (size_t)d * SL + n0 + noct * 8);
            #pragma unroll
            for (int j = 0; j < 8; ++j) xT[noct * 8 + j][d] = U.s[j];
        }
    }
    // stage w [o][k] fp32 -> bf16
    #pragma unroll
    for (int itr = 0; itr < 4; ++itr) {
        const int o = itr * 32 + (t >> 3);
        const int f = (t & 7) * 16;
        const float* src = wq + (size_t)(o0 + o) * 128 + f;
        float4 a = *(const float4*)src;
        float4 b = *(const float4*)(src + 4);
        float4 c = *(const float4*)(src + 8);
        float4 d2 = *(const float4*)(src + 12);
        *(uint4*)&wT[o][f] = pack8(a, b);
        *(uint4*)&wT[o][f + 8] = pack8(c, d2);
    }
    if (t < 128) bs[t] = bq[o0 + t];
    __syncthreads();

    const int lane = t & 63, wv = t >> 6, lo = lane & 15, hi = lane >> 4;

    bf16x8 af[2][4];
    #pragma unroll
    for (int om = 0; om < 2; ++om)
        #pragma unroll
        for (int ks = 0; ks < 4; ++ks)
            af[om][ks] = *(const bf16x8*)&wT[wv * 32 + om * 16 + lo][hi * 8 + ks * 32];

    u16* tbuf = (ot == 0) ? qT : kT;

    #pragma unroll
    for (int nt = 0; nt < 4; ++nt) {
        bf16x8 bfr[4];
        #pragma unroll
        for (int ks = 0; ks < 4; ++ks)
            bfr[ks] = *(const bf16x8*)&xT[nt * 16 + lo][hi * 8 + ks * 32];
        #pragma unroll
        for (int om = 0; om < 2; ++om) {
            f32x4 acc = {0.f, 0.f, 0.f, 0.f};
            #pragma unroll
            for (int ks = 0; ks < 4; ++ks)
                acc = MFMA16(af[om][ks], bfr[ks], acc);
            if (ot < 2) {
                // lane holds out[n = n0+nt*16+lo][c = om*16+hi*4+r], head = wv
                ushort4 o4;
                o4.x = f2bf(acc[0] + bs[wv * 32 + om * 16 + hi * 4 + 0]);
                o4.y = f2bf(acc[1] + bs[wv * 32 + om * 16 + hi * 4 + 1]);
                o4.z = f2bf(acc[2] + bs[wv * 32 + om * 16 + hi * 4 + 2]);
                o4.w = f2bf(acc[3] + bs[wv * 32 + om * 16 + hi * 4 + 3]);
                *(ushort4*)(tbuf + (size_t)wv * SL * 32
                            + (size_t)(n0 + nt * 16 + lo) * 32 + om * 16 + hi * 4) = o4;
            } else {
                // V native: row o = wv*32+om*16+hi*4+r, col n0+nt*16+lo
                #pragma unroll
                for (int r = 0; r < 4; ++r) {
                    const int o = wv * 32 + om * 16 + hi * 4 + r;
                    vb[(size_t)o * SL + n0 + nt * 16 + lo] = f2bf(acc[r] + bs[o]);
                }
            }
        }
    }
}

// ---------------------------------------------------------------------------
// Attention, zero-staging: Q/K fragments direct from qT/kT[h][n][32] (fully
// coalesced 64B rows), V direct from vb[c][n]. Only P transits per-wave LDS
// (no barriers anywhere). Output stored direct from accumulators.
// ---------------------------------------------------------------------------
template<int KLEN>
__global__ __launch_bounds__(256, 4) void attn_kernel(const u16* __restrict__ qT,
                                                      const u16* __restrict__ kT,
                                                      const u16* __restrict__ vb,
                                                      u16* __restrict__ ao) {
    constexpr int NJT = KLEN / 16;
    constexpr int IT = (KLEN == 256) ? 4 : 2;
    constexpr int NOUT = SL / KLEN;
    __shared__ u16 PT[4][16][36];

    const int bid = blockIdx.x;
    const int it = bid & (IT - 1);
    const int outer = (bid / IT) % NOUT;
    const int h = bid / (IT * NOUT);
    const int base = outer * KLEN;
    const int i0 = it * 64;
    const int t = threadIdx.x;
    const int lane = t & 63, wv = t >> 6, lo = lane & 15, hi = lane >> 4;

    const u16* qh = qT + (size_t)h * SL * 32;
    const u16* kh = kT + (size_t)h * SL * 32;
    const u16* vh = vb + (size_t)h * 32 * SL;

    bf16x8 qfrag = *(const bf16x8*)(qh + (size_t)(base + i0 + wv * 16 + lo) * 32 + hi * 8);
    u16 (*pt)[36] = PT[wv];

    f32x4 oacc0 = {0.f, 0.f, 0.f, 0.f}, oacc1 = {0.f, 0.f, 0.f, 0.f};
    float lsum[4] = {0.f, 0.f, 0.f, 0.f};

    #pragma unroll
    for (int jt = 0; jt < NJT; ++jt) {
        bf16x8 kfrag = *(const bf16x8*)(kh + (size_t)(base + jt * 16 + lo) * 32 + hi * 8);
        f32x4 z = {0.f, 0.f, 0.f, 0.f};
        f32x4 s = MFMA16(qfrag, kfrag, z);
        #pragma unroll
        for (int r = 0; r < 4; ++r) {
            float p = __expf(s[r]);
            lsum[r] += p;
            pt[hi * 4 + r][(jt & 1) * 16 + lo] = f2bf(p);
        }
        if (jt & 1) {
            const int jb = (jt - 1) * 16;
            bf16x8 pfrag = *(const bf16x8*)&pt[lo][hi * 8];
            bf16x8 v0 = *(const bf16x8*)(vh + (size_t)lo * SL + base + jb + hi * 8);
            bf16x8 v1 = *(const bf16x8*)(vh + (size_t)(16 + lo) * SL + base + jb + hi * 8);
            oacc0 = MFMA16(pfrag, v0, oacc0);
            oacc1 = MFMA16(pfrag, v1, oacc1);
        }
    }
    #pragma unroll
    for (int r = 0; r < 4; ++r) {
        float v = lsum[r];
        v += __shfl_xor(v, 1);
        v += __shfl_xor(v, 2);
        v += __shfl_xor(v, 4);
        v += __shfl_xor(v, 8);
        lsum[r] = 1.f / v;
    }
    // lane holds O[i = i0+wv*16+hi*4+r][d = lo (oacc0) / 16+lo (oacc1)]
    {
        ushort4 o4;
        o4.x = f2bf(oacc0[0] * lsum[0]);
        o4.y = f2bf(oacc0[1] * lsum[1]);
        o4.z = f2bf(oacc0[2] * lsum[2]);
        o4.w = f2bf(oacc0[3] * lsum[3]);
        *(ushort4*)(ao + (size_t)(h * 32 + lo) * SL + base + i0 + wv * 16 + hi * 4) = o4;
        o4.x = f2bf(oacc1[0] * lsum[0]);
        o4.y = f2bf(oacc1[1] * lsum[1]);
        o4.z = f2bf(oacc1[2] * lsum[2]);
        o4.w = f2bf(oacc1[3] * lsum[3]);
        *(ushort4*)(ao + (size_t)(h * 32 + 16 + lo) * SL + base + i0 + wv * 16 + hi * 4) = o4;
    }
}

// ---------------------------------------------------------------------------
// Fused LN: stats + normalize + transpose (round-8 version, verified).
// ---------------------------------------------------------------------------
template<int NIN, typename T0, typename TO>
__global__ __launch_bounds__(256) void ln_fused(const T0* __restrict__ in0,
                                                const u16* __restrict__ in1,
                                                const float* __restrict__ g,
                                                const float* __restrict__ be,
                                                TO* __restrict__ outp) {
    constexpr int NOUT = SL / NIN;
    constexpr int CT = NIN / 16;
    __shared__ float val[128][69];
    __shared__ float redS[4][72];
    __shared__ float redQ[4][72];
    __shared__ float stat[64][2];
    const int bid = blockIdx.x;
    const int r0 = (bid / CT) * 4;
    const int c0 = (bid % CT) * 16;
    const int t = threadIdx.x;
    const int pos = t & 63, q = t >> 6;
    const size_t gp = (size_t)(r0 + (pos >> 4)) * NIN + c0 + (pos & 15);

    float s = 0.f, ss = 0.f;
    #pragma unroll 4
    for (int dd = 0; dd < 32; ++dd) {
        const int d = q * 32 + dd;
        float v;
        if constexpr (sizeof(T0) == 4) v = ((const float*)in0)[(size_t)d * SL + gp];
        else                           v = bf2f(((const u16*)in0)[(size_t)d * SL + gp]);
        v += bf2f(in1[(size_t)d * SL + gp]);
        val[d][pos] = v;
        s += v; ss += v * v;
    }
    redS[q][pos] = s;
    redQ[q][pos] = ss;
    __syncthreads();
    if (t < 64) {
        const float S  = redS[0][t] + redS[1][t] + redS[2][t] + redS[3][t];
        const float SS = redQ[0][t] + redQ[1][t] + redQ[2][t] + redQ[3][t];
        const float mean = S * (1.f / 128.f);
        const float var  = SS * (1.f / 128.f) - mean * mean;
        stat[t][0] = mean;
        stat[t][1] = rsqrtf(var + EPS_LN);
    }
    __syncthreads();

    {   // write phase: thread = (d = t>>1, 8 c's)
        const int d = t >> 1;
        const int ch = (t & 1) * 8;
        const float gd = g[d], bd = be[d];
        #pragma unroll
        for (int cc = 0; cc < 8; ++cc) {
            const int c = ch + cc;
            float ov[4];
            #pragma unroll
            for (int r = 0; r < 4; ++r) {
                const int p = r * 16 + c;
                ov[r] = (val[d][p] - stat[p][0]) * stat[p][1] * gd + bd;
            }
            if constexpr (sizeof(TO) == 4) {
                float* dst = (float*)outp + (size_t)d * SL + (c0 + c) * NOUT + r0;
                *(float4*)dst = make_float4(ov[0], ov[1], ov[2], ov[3]);
            } else {
                u16* dst = (u16*)outp + (size_t)d * SL + (c0 + c) * NOUT + r0;
                ushort4 o4;
                o4.x = f2bf(ov[0]); o4.y = f2bf(ov[1]);
                o4.z = f2bf(ov[2]); o4.w = f2bf(ov[3]);
                *(ushort4*)dst = o4;
            }
        }
    }
}

// ---------------------------------------------------------------------------
extern "C" void kernel_launch(void* const* d_in, const int* in_sizes, int n_in,
                              void* d_out, int out_size, void* d_ws, size_t ws_size,
                              hipStream_t stream) {
    const float* x     = (const float*)d_in[0];
    const float* w_row = (const float*)d_in[1];
    const float* b_row = (const float*)d_in[2];
    const float* w_col = (const float*)d_in[3];
    const float* b_col = (const float*)d_in[4];
    const float* g1    = (const float*)d_in[5];
    const float* be1   = (const float*)d_in[6];
    const float* g2    = (const float*)d_in[7];
    const float* be2   = (const float*)d_in[8];
    float* out = (float*)d_out;

    // ws: qT 8MB | kT 8MB | vb 8MB | ao 8MB | o1b 8MB
    char* base = (char*)d_ws;
    u16* qTb = (u16*)base;                        base += (size_t)128 * SL * 2;
    u16* kTb = (u16*)base;                        base += (size_t)128 * SL * 2;
    u16* vbb = (u16*)base;                        base += (size_t)128 * SL * 2;
    u16* ao16 = (u16*)base;                       base += (size_t)128 * SL * 2;
    u16* o1b  = (u16*)base;

    qkv_mfma<float><<<1536, 256, 0, stream>>>(x, w_row, b_row, qTb, kTb, vbb);
    attn_kernel<256><<<2048, 256, 0, stream>>>(qTb, kTb, vbb, ao16);
    ln_fused<256, float, u16><<<512, 256, 0, stream>>>(x, ao16, g1, be1, o1b);
    qkv_mfma<u16><<<1536, 256, 0, stream>>>(o1b, w_col, b_col, qTb, kTb, vbb);
    attn_kernel<128><<<2048, 256, 0, stream>>>(qTb, kTb, vbb, ao16);
    ln_fused<128, u16, float><<<512, 256, 0, stream>>>(o1b, ao16, g2, be2, out);
}

// Round 10
// 107.037 us; speedup vs baseline: 1.3318x; 1.1183x over previous
//
#include <hip/hip_runtime.h>
#include <hip/hip_bf16.h>

#define SL     32768
#define EPS_LN 1e-5f

typedef unsigned short u16;
typedef __attribute__((ext_vector_type(8))) short bf16x8;
typedef __attribute__((ext_vector_type(4))) float f32x4;

#define MFMA16(a, b, c) __builtin_amdgcn_mfma_f32_16x16x32_bf16((a), (b), (c), 0, 0, 0)

__device__ inline u16 f2bf(float f) {
    __hip_bfloat16 h = __float2bfloat16(f);
    return *reinterpret_cast<u16*>(&h);
}
__device__ inline float bf2f(u16 u) {
    unsigned v = ((unsigned)u) << 16;
    float f;
    __builtin_memcpy(&f, &v, 4);
    return f;
}
__device__ inline uint4 pack8(float4 a, float4 b) {
    union { uint4 v; u16 u[8]; } U;
    U.u[0] = f2bf(a.x); U.u[1] = f2bf(a.y); U.u[2] = f2bf(a.z); U.u[3] = f2bf(a.w);
    U.u[4] = f2bf(b.x); U.u[5] = f2bf(b.y); U.u[6] = f2bf(b.z); U.u[7] = f2bf(b.w);
    return U.v;
}

// ---------------------------------------------------------------------------
// wcast: w_row, w_col -> bf16 once. 12288 threads, 8 elems each.
// ---------------------------------------------------------------------------
__global__ __launch_bounds__(256) void wcast_kernel(const float* __restrict__ wr,
                                                    const float* __restrict__ wc,
                                                    u16* __restrict__ wrb,
                                                    u16* __restrict__ wcb) {
    const int i = blockIdx.x * 256 + threadIdx.x;
    const int NW = 384 * 128 / 8;   // 6144
    const float* src = (i < NW) ? wr : wc;
    u16* dst = (i < NW) ? wrb : wcb;
    const int j = (i < NW) ? i : i - NW;
    float4 a = ((const float4*)src)[j * 2];
    float4 b = ((const float4*)src)[j * 2 + 1];
    ((uint4*)dst)[j] = pack8(a, b);
}

// ---------------------------------------------------------------------------
// QKV via MFMA. grid 1536 = 3 o-tiles(128) x 512 n-tiles(64).
// w fragments loaded DIRECT from global bf16 (no LDS); x staged in LDS.
// o-tile 0 -> qT[h][n][32], 1 -> kT[h][n][32], 2 -> vb[c][n] native.
// ---------------------------------------------------------------------------
template<typename T>
__global__ __launch_bounds__(256) void qkv_mfma(const T* __restrict__ in,
                                                const u16* __restrict__ wb,
                                                const float* __restrict__ bq,
                                                u16* __restrict__ qT,
                                                u16* __restrict__ kT,
                                                u16* __restrict__ vb) {
    __shared__ u16 xT[64][136];
    __shared__ float bs[128];
    const int bid = blockIdx.x;
    const int ot = bid % 3;
    const int o0 = ot * 128;
    const int n0 = (bid / 3) * 64;
    const int t = threadIdx.x;
    const int lane = t & 63, wv = t >> 6, lo = lane & 15, hi = lane >> 4;

    // A-fragments direct from global (each frag-load = 16 rows x 64B lines)
    bf16x8 af[2][4];
    #pragma unroll
    for (int om = 0; om < 2; ++om)
        #pragma unroll
        for (int ks = 0; ks < 4; ++ks)
            af[om][ks] = *(const bf16x8*)(wb + (size_t)(o0 + wv * 32 + om * 16 + lo) * 128
                                             + hi * 8 + ks * 32);

    // stage x transposed [n][d]; conflict-free map (64 d-lanes per wave)
    #pragma unroll
    for (int itr = 0; itr < 4; ++itr) {
        const int u = t + itr * 256;
        const int d = u & 127, noct = u >> 7;
        if constexpr (sizeof(T) == 4) {
            const float* src = (const float*)in + (size_t)d * SL + n0 + noct * 8;
            float4 f0 = *(const float4*)src;
            float4 f1 = *(const float4*)(src + 4);
            xT[noct * 8 + 0][d] = f2bf(f0.x);
            xT[noct * 8 + 1][d] = f2bf(f0.y);
            xT[noct * 8 + 2][d] = f2bf(f0.z);
            xT[noct * 8 + 3][d] = f2bf(f0.w);
            xT[noct * 8 + 4][d] = f2bf(f1.x);
            xT[noct * 8 + 5][d] = f2bf(f1.y);
            xT[noct * 8 + 6][d] = f2bf(f1.z);
            xT[noct * 8 + 7][d] = f2bf(f1.w);
        } else {
            union { uint4 v; u16 s[8]; } U;
            U.v = *(const uint4*)((const u16*)in + (size_t)d * SL + n0 + noct * 8);
            #pragma unroll
            for (int j = 0; j < 8; ++j) xT[noct * 8 + j][d] = U.s[j];
        }
    }
    if (t < 128) bs[t] = bq[o0 + t];
    __syncthreads();

    u16* tbuf = (ot == 0) ? qT : kT;

    #pragma unroll
    for (int nt = 0; nt < 4; ++nt) {
        bf16x8 bfr[4];
        #pragma unroll
        for (int ks = 0; ks < 4; ++ks)
            bfr[ks] = *(const bf16x8*)&xT[nt * 16 + lo][hi * 8 + ks * 32];
        #pragma unroll
        for (int om = 0; om < 2; ++om) {
            f32x4 acc = {0.f, 0.f, 0.f, 0.f};
            #pragma unroll
            for (int ks = 0; ks < 4; ++ks)
                acc = MFMA16(af[om][ks], bfr[ks], acc);
            if (ot < 2) {
                ushort4 o4;
                o4.x = f2bf(acc[0] + bs[wv * 32 + om * 16 + hi * 4 + 0]);
                o4.y = f2bf(acc[1] + bs[wv * 32 + om * 16 + hi * 4 + 1]);
                o4.z = f2bf(acc[2] + bs[wv * 32 + om * 16 + hi * 4 + 2]);
                o4.w = f2bf(acc[3] + bs[wv * 32 + om * 16 + hi * 4 + 3]);
                *(ushort4*)(tbuf + (size_t)wv * SL * 32
                            + (size_t)(n0 + nt * 16 + lo) * 32 + om * 16 + hi * 4) = o4;
            } else {
                #pragma unroll
                for (int r = 0; r < 4; ++r) {
                    const int o = wv * 32 + om * 16 + hi * 4 + r;
                    vb[(size_t)o * SL + n0 + nt * 16 + lo] = f2bf(acc[r] + bs[o]);
                }
            }
        }
    }
}

// ---------------------------------------------------------------------------
// Attention v2: one block per (h,outer) covers ALL KLEN queries. Wave = 32
// queries (2 subs of 16) -> K/V fragments loaded once, shared by 2/4 MFMAs.
// Zero staging of Q/K/V; only P transits per-wave LDS. No barriers.
// ---------------------------------------------------------------------------
template<int KLEN, int NTHR>
__global__ __launch_bounds__(NTHR) void attn_kernel(const u16* __restrict__ qT,
                                                    const u16* __restrict__ kT,
                                                    const u16* __restrict__ vb,
                                                    u16* __restrict__ ao) {
    constexpr int NJT = KLEN / 16;
    constexpr int NW = NTHR / 64;          // 8 (KLEN=256) / 4 (KLEN=128)
    constexpr int NOUT = SL / KLEN;
    __shared__ u16 PT[NW][2][16][36];

    const int bid = blockIdx.x;
    const int outer = bid % NOUT;
    const int h = bid / NOUT;
    const int base = outer * KLEN;
    const int t = threadIdx.x;
    const int lane = t & 63, wv = t >> 6, lo = lane & 15, hi = lane >> 4;
    const int i0w = wv * 32;

    const u16* qh = qT + (size_t)h * SL * 32;
    const u16* kh = kT + (size_t)h * SL * 32;
    const u16* vh = vb + (size_t)h * 32 * SL;

    bf16x8 qf0 = *(const bf16x8*)(qh + (size_t)(base + i0w + lo) * 32 + hi * 8);
    bf16x8 qf1 = *(const bf16x8*)(qh + (size_t)(base + i0w + 16 + lo) * 32 + hi * 8);

    f32x4 o00 = {0.f, 0.f, 0.f, 0.f}, o01 = {0.f, 0.f, 0.f, 0.f};
    f32x4 o10 = {0.f, 0.f, 0.f, 0.f}, o11 = {0.f, 0.f, 0.f, 0.f};
    float ls0[4] = {0.f, 0.f, 0.f, 0.f};
    float ls1[4] = {0.f, 0.f, 0.f, 0.f};

    #pragma unroll
    for (int jt = 0; jt < NJT; ++jt) {
        bf16x8 kf = *(const bf16x8*)(kh + (size_t)(base + jt * 16 + lo) * 32 + hi * 8);
        f32x4 z = {0.f, 0.f, 0.f, 0.f};
        f32x4 s0 = MFMA16(qf0, kf, z);
        f32x4 s1 = MFMA16(qf1, kf, z);
        #pragma unroll
        for (int r = 0; r < 4; ++r) {
            float p0 = __expf(s0[r]);
            ls0[r] += p0;
            PT[wv][0][hi * 4 + r][(jt & 1) * 16 + lo] = f2bf(p0);
            float p1 = __expf(s1[r]);
            ls1[r] += p1;
            PT[wv][1][hi * 4 + r][(jt & 1) * 16 + lo] = f2bf(p1);
        }
        if (jt & 1) {
            const int jb = (jt - 1) * 16;
            bf16x8 pf0 = *(const bf16x8*)&PT[wv][0][lo][hi * 8];
            bf16x8 pf1 = *(const bf16x8*)&PT[wv][1][lo][hi * 8];
            bf16x8 v0 = *(const bf16x8*)(vh + (size_t)lo * SL + base + jb + hi * 8);
            bf16x8 v1 = *(const bf16x8*)(vh + (size_t)(16 + lo) * SL + base + jb + hi * 8);
            o00 = MFMA16(pf0, v0, o00);
            o01 = MFMA16(pf0, v1, o01);
            o10 = MFMA16(pf1, v0, o10);
            o11 = MFMA16(pf1, v1, o11);
        }
    }
    #pragma unroll
    for (int r = 0; r < 4; ++r) {
        float v0 = ls0[r];
        v0 += __shfl_xor(v0, 1);
        v0 += __shfl_xor(v0, 2);
        v0 += __shfl_xor(v0, 4);
        v0 += __shfl_xor(v0, 8);
        ls0[r] = 1.f / v0;
        float v1 = ls1[r];
        v1 += __shfl_xor(v1, 1);
        v1 += __shfl_xor(v1, 2);
        v1 += __shfl_xor(v1, 4);
        v1 += __shfl_xor(v1, 8);
        ls1[r] = 1.f / v1;
    }
    {   // stores: lane covers O[i][d=lo] and O[i][d=16+lo], subs at i0w / i0w+16
        ushort4 o4;
        o4.x = f2bf(o00[0] * ls0[0]);
        o4.y = f2bf(o00[1] * ls0[1]);
        o4.z = f2bf(o00[2] * ls0[2]);
        o4.w = f2bf(o00[3] * ls0[3]);
        *(ushort4*)(ao + (size_t)(h * 32 + lo) * SL + base + i0w + hi * 4) = o4;
        o4.x = f2bf(o01[0] * ls0[0]);
        o4.y = f2bf(o01[1] * ls0[1]);
        o4.z = f2bf(o01[2] * ls0[2]);
        o4.w = f2bf(o01[3] * ls0[3]);
        *(ushort4*)(ao + (size_t)(h * 32 + 16 + lo) * SL + base + i0w + hi * 4) = o4;
        o4.x = f2bf(o10[0] * ls1[0]);
        o4.y = f2bf(o10[1] * ls1[1]);
        o4.z = f2bf(o10[2] * ls1[2]);
        o4.w = f2bf(o10[3] * ls1[3]);
        *(ushort4*)(ao + (size_t)(h * 32 + lo) * SL + base + i0w + 16 + hi * 4) = o4;
        o4.x = f2bf(o11[0] * ls1[0]);
        o4.y = f2bf(o11[1] * ls1[1]);
        o4.z = f2bf(o11[2] * ls1[2]);
        o4.w = f2bf(o11[3] * ls1[3]);
        *(ushort4*)(ao + (size_t)(h * 32 + 16 + lo) * SL + base + i0w + 16 + hi * 4) = o4;
    }
}

// ---------------------------------------------------------------------------
// Fused LN: stats + normalize + transpose (verified rounds 8-9).
// ---------------------------------------------------------------------------
template<int NIN, typename T0, typename TO>
__global__ __launch_bounds__(256) void ln_fused(const T0* __restrict__ in0,
                                                const u16* __restrict__ in1,
                                                const float* __restrict__ g,
                                                const float* __restrict__ be,
                                                TO* __restrict__ outp) {
    constexpr int NOUT = SL / NIN;
    constexpr int CT = NIN / 16;
    __shared__ float val[128][69];
    __shared__ float redS[4][72];
    __shared__ float redQ[4][72];
    __shared__ float stat[64][2];
    const int bid = blockIdx.x;
    const int r0 = (bid / CT) * 4;
    const int c0 = (bid % CT) * 16;
    const int t = threadIdx.x;
    const int pos = t & 63, q = t >> 6;
    const size_t gp = (size_t)(r0 + (pos >> 4)) * NIN + c0 + (pos & 15);

    float s = 0.f, ss = 0.f;
    #pragma unroll 4
    for (int dd = 0; dd < 32; ++dd) {
        const int d = q * 32 + dd;
        float v;
        if constexpr (sizeof(T0) == 4) v = ((const float*)in0)[(size_t)d * SL + gp];
        else                           v = bf2f(((const u16*)in0)[(size_t)d * SL + gp]);
        v += bf2f(in1[(size_t)d * SL + gp]);
        val[d][pos] = v;
        s += v; ss += v * v;
    }
    redS[q][pos] = s;
    redQ[q][pos] = ss;
    __syncthreads();
    if (t < 64) {
        const float S  = redS[0][t] + redS[1][t] + redS[2][t] + redS[3][t];
        const float SS = redQ[0][t] + redQ[1][t] + redQ[2][t] + redQ[3][t];
        const float mean = S * (1.f / 128.f);
        const float var  = SS * (1.f / 128.f) - mean * mean;
        stat[t][0] = mean;
        stat[t][1] = rsqrtf(var + EPS_LN);
    }
    __syncthreads();

    {   // write phase: thread = (d = t>>1, 8 c's)
        const int d = t >> 1;
        const int ch = (t & 1) * 8;
        const float gd = g[d], bd = be[d];
        #pragma unroll
        for (int cc = 0; cc < 8; ++cc) {
            const int c = ch + cc;
            float ov[4];
            #pragma unroll
            for (int r = 0; r < 4; ++r) {
                const int p = r * 16 + c;
                ov[r] = (val[d][p] - stat[p][0]) * stat[p][1] * gd + bd;
            }
            if constexpr (sizeof(TO) == 4) {
                float* dst = (float*)outp + (size_t)d * SL + (c0 + c) * NOUT + r0;
                *(float4*)dst = make_float4(ov[0], ov[1], ov[2], ov[3]);
            } else {
                u16* dst = (u16*)outp + (size_t)d * SL + (c0 + c) * NOUT + r0;
                ushort4 o4;
                o4.x = f2bf(ov[0]); o4.y = f2bf(ov[1]);
                o4.z = f2bf(ov[2]); o4.w = f2bf(ov[3]);
                *(ushort4*)dst = o4;
            }
        }
    }
}

// ---------------------------------------------------------------------------
extern "C" void kernel_launch(void* const* d_in, const int* in_sizes, int n_in,
                              void* d_out, int out_size, void* d_ws, size_t ws_size,
                              hipStream_t stream) {
    const float* x     = (const float*)d_in[0];
    const float* w_row = (const float*)d_in[1];
    const float* b_row = (const float*)d_in[2];
    const float* w_col = (const float*)d_in[3];
    const float* b_col = (const float*)d_in[4];
    const float* g1    = (const float*)d_in[5];
    const float* be1   = (const float*)d_in[6];
    const float* g2    = (const float*)d_in[7];
    const float* be2   = (const float*)d_in[8];
    float* out = (float*)d_out;

    // ws: qT 8MB | kT 8MB | vb 8MB | ao 8MB | o1b 8MB | wrb 96KB | wcb 96KB
    char* base = (char*)d_ws;
    u16* qTb = (u16*)base;                        base += (size_t)128 * SL * 2;
    u16* kTb = (u16*)base;                        base += (size_t)128 * SL * 2;
    u16* vbb = (u16*)base;                        base += (size_t)128 * SL * 2;
    u16* ao16 = (u16*)base;                       base += (size_t)128 * SL * 2;
    u16* o1b  = (u16*)base;                       base += (size_t)128 * SL * 2;
    u16* wrb  = (u16*)base;                       base += (size_t)384 * 128 * 2;
    u16* wcb  = (u16*)base;

    wcast_kernel<<<48, 256, 0, stream>>>(w_row, w_col, wrb, wcb);
    qkv_mfma<float><<<1536, 256, 0, stream>>>(x, wrb, b_row, qTb, kTb, vbb);
    attn_kernel<256, 512><<<512, 512, 0, stream>>>(qTb, kTb, vbb, ao16);
    ln_fused<256, float, u16><<<512, 256, 0, stream>>>(x, ao16, g1, be1, o1b);
    qkv_mfma<u16><<<1536, 256, 0, stream>>>(o1b, wcb, b_col, qTb, kTb, vbb);
    attn_kernel<128, 256><<<1024, 256, 0, stream>>>(qTb, kTb, vbb, ao16);
    ln_fused<128, u16, float><<<512, 256, 0, stream>>>(o1b, ao16, g2, be2, out);
}